// Round 5
// baseline (432.769 us; speedup 1.0000x reference)
//
#include <hip/hip_runtime.h>
#include <hip/hip_bf16.h>

typedef _Float16 f16;
typedef _Float16 f16x4 __attribute__((ext_vector_type(4)));
typedef _Float16 f16x8 __attribute__((ext_vector_type(8)));
typedef float f32x4 __attribute__((ext_vector_type(4)));

constexpr int BATCH = 4, C = 512, CQ = 128, N = 4096;
constexpr int FKD = 256; // f(128) + k(128) channels, stacked
constexpr int NT = 32;   // 4096 / 128 j-tiles

// workspace layout (bytes)
constexpr size_t WS_XT   = 0;                                      // f16 [B][N][C]   16 MB
constexpr size_t WS_FK   = WS_XT   + (size_t)BATCH * N * C * 2;    // f16 [B][N][256]  8 MB
constexpr size_t WS_V    = WS_FK   + (size_t)BATCH * N * FKD * 2;  // f16 [B][C][N]   16 MB
constexpr size_t WS_WCAT = WS_V    + (size_t)BATCH * C * N * 2;    // f16 [256][512]
constexpr size_t WS_WL   = WS_WCAT + (size_t)FKD * C * 2;          // f16 [512][512]
constexpr size_t WS_BC   = WS_WL   + (size_t)C * C * 2;            // f32 [256]

#define AS1(p) ((const __attribute__((address_space(1))) void*)(p))
#define AS3(p) ((__attribute__((address_space(3))) void*)(p))

// ---------------------------------------------------------------- weights->fp16
__global__ void prep_weights(const float* __restrict__ Wf_w, const float* __restrict__ Wf_b,
                             const float* __restrict__ Wh_w, const float* __restrict__ Wh_b,
                             const float* __restrict__ Wl_w,
                             f16* __restrict__ wcat, f16* __restrict__ wl, float* __restrict__ bcat) {
    int i = blockIdx.x * 256 + threadIdx.x;                 // grid covers C*C
    if (i < FKD * C) {
        int o = i >> 9, c = i & 511;
        float v = (o < CQ) ? Wf_w[o * C + c] : Wh_w[(o - CQ) * C + c];
        wcat[i] = (f16)v;
    }
    if (i < C * C) wl[i] = (f16)Wl_w[i];
    if (i < FKD) bcat[i] = (i < CQ) ? Wf_b[i] : Wh_b[i - CQ];
}

// ---------------------------------------------------------------- x (B,C,N) f32 -> xT (B,N,C) f16
__global__ void transpose_x(const float* __restrict__ x, f16* __restrict__ xt) {
    __shared__ float tile[64][65];
    int gid = blockIdx.x;
    int b = gid >> 9, rem = gid & 511;
    int c0 = (rem >> 6) * 64, n0 = (rem & 63) * 64;
    int t = threadIdx.x;
    int tn = t & 63, tg = t >> 6;
    const float* xp = x + (size_t)b * C * N + (size_t)c0 * N + n0;
#pragma unroll
    for (int r = 0; r < 16; ++r) {
        int cl = tg + r * 4;
        tile[cl][tn] = xp[(size_t)cl * N + tn];
    }
    __syncthreads();
    f16* xo = xt + (size_t)b * N * C + (size_t)n0 * C + c0;
#pragma unroll
    for (int r = 0; r < 16; ++r) {
        int nl = tg + r * 4;
        xo[(size_t)nl * C + tn] = (f16)tile[tn][nl];
    }
}

// ---------------------------------------------------------------- FK projection (64n x 64o per wave)
__global__ void __launch_bounds__(256) proj_fk(const f16* __restrict__ xt, const f16* __restrict__ wcat,
                                               const float* __restrict__ bcat, f16* __restrict__ fk) {
    int wid = blockIdx.x * 4 + (threadIdx.x >> 6);   // 1024 waves: b(2) nt(6) ot(2)
    int lane = threadIdx.x & 63;
    int li = lane & 15, lg = lane >> 4;
    int b  = wid >> 8;
    int nt = (wid >> 2) & 63;
    int ot = wid & 3;
    int n0 = nt * 64, o0 = ot * 64;
    const f16* ap = xt + (size_t)(b * N + n0 + li) * C + lg * 8;
    const f16* bp = wcat + (size_t)(o0 + li) * C + lg * 8;
    f32x4 acc[4][4] = {};
    for (int ks = 0; ks < 16; ++ks) {
        f16x8 a4[4], b4[4];
#pragma unroll
        for (int t = 0; t < 4; ++t) a4[t] = *(const f16x8*)(ap + (size_t)(t * 16) * C + ks * 32);
#pragma unroll
        for (int t = 0; t < 4; ++t) b4[t] = *(const f16x8*)(bp + (size_t)(t * 16) * C + ks * 32);
#pragma unroll
        for (int tA = 0; tA < 4; ++tA)
#pragma unroll
            for (int tB = 0; tB < 4; ++tB)
                acc[tA][tB] = __builtin_amdgcn_mfma_f32_16x16x32_f16(a4[tA], b4[tB], acc[tA][tB], 0, 0, 0);
    }
#pragma unroll
    for (int tB = 0; tB < 4; ++tB) {
        int o = o0 + tB * 16 + li;
        float bias = bcat[o];
#pragma unroll
        for (int tA = 0; tA < 4; ++tA)
#pragma unroll
            for (int r = 0; r < 4; ++r) {
                int n = n0 + tA * 16 + lg * 4 + r;
                fk[(size_t)(b * N + n) * FKD + o] = (f16)(acc[tA][tB][r] + bias);
            }
    }
}

// ---------------------------------------------------------------- V projection (64c x 64n per wave)
__global__ void __launch_bounds__(256) proj_v(const f16* __restrict__ xt, const f16* __restrict__ wl,
                                              const float* __restrict__ wlb, f16* __restrict__ v) {
    int wid = blockIdx.x * 4 + (threadIdx.x >> 6);   // 2048 waves: b(2) ct(3) nt(6)
    int lane = threadIdx.x & 63;
    int li = lane & 15, lg = lane >> 4;
    int b  = wid >> 9;
    int ct = (wid >> 6) & 7;
    int nt = wid & 63;
    int c0 = ct * 64, n0 = nt * 64;
    const f16* ap = wl + (size_t)(c0 + li) * C + lg * 8;
    const f16* bp = xt + (size_t)(b * N + n0 + li) * C + lg * 8;
    f32x4 acc[4][4] = {};
    for (int ks = 0; ks < 16; ++ks) {
        f16x8 a4[4], b4[4];
#pragma unroll
        for (int t = 0; t < 4; ++t) a4[t] = *(const f16x8*)(ap + (size_t)(t * 16) * C + ks * 32);
#pragma unroll
        for (int t = 0; t < 4; ++t) b4[t] = *(const f16x8*)(bp + (size_t)(t * 16) * C + ks * 32);
#pragma unroll
        for (int tA = 0; tA < 4; ++tA)
#pragma unroll
            for (int tB = 0; tB < 4; ++tB)
                acc[tA][tB] = __builtin_amdgcn_mfma_f32_16x16x32_f16(a4[tA], b4[tB], acc[tA][tB], 0, 0, 0);
    }
#pragma unroll
    for (int tA = 0; tA < 4; ++tA)
#pragma unroll
        for (int r = 0; r < 4; ++r) {
            int c = c0 + tA * 16 + lg * 4 + r;
            float bias = wlb[c];
#pragma unroll
            for (int tB = 0; tB < 4; ++tB) {
                int n = n0 + tB * 16 + li;
                v[(size_t)(b * C + c) * N + n] = (f16)(acc[tA][tB][r] + bias);
            }
        }
}

// ---------------------------------------------------------------- flash attention + residual (v5)
// Block = 16 waves (1024 thr), one 64-query tile. Wave = (ws=wv>>1, h=wv&1):
//   QK: j-slice ws (16 rows of the 128-j tile), i-half h (2 i-frags) -> 8 MFMA
//   PV: c-slice ws*64 (4 c-frags), i-half h (2 i-frags), all 128 j  -> 32 MFMA
// K tile (128x128, 32KB) double-buffered via global_load_lds (linear LDS dest,
// inverse-swizzled global source; readers XOR granule with row&7 -> rule 21 ok).
// P[64][128] f16 shared, granule-swizzled ^(row&7). 2 barriers/iter.
// Grid 256 = 1 block/CU (LDS 84KB), 16 waves/CU = 4 waves/SIMD. XCD-pinned batches.
__global__ void __launch_bounds__(1024, 4) attn(const f16* __restrict__ fk, const f16* __restrict__ v,
                                                const float* __restrict__ x, const float* __restrict__ alphap,
                                                float* __restrict__ out) {
    __shared__ __align__(16) f16 kbuf[2][128 * 128];   // 64 KB
    __shared__ __align__(16) f16 pbuf[64 * 128];       // 16 KB
    __shared__ float smax[2][8][2][16];                // [h][ws][f][li]
    __shared__ float ssum[2][8][2][16];

    const int tid  = threadIdx.x;
    const int wv   = tid >> 6;        // 0..15
    const int lane = tid & 63;
    const int li = lane & 15, lg = lane >> 4;
    const int swl = li & 7;
    const int ws = wv >> 1;           // j-slice (QK) / c-slice (PV)
    const int h  = wv & 1;            // i-half
    // XCD-pinning: under blk%8 round-robin, each XCD sees a single batch
    const int v0 = blockIdx.x;
    const int b  = (v0 & 7) >> 1;
    const int it = ((v0 & 1) << 5) | (v0 >> 3);
    const int i0 = it * 64;
    const int c0 = ws * 64;

    // F fragments (B operand of swapped QK), own i-half: i = i0 + h*32 + f*16 + li
    f16x8 fb[2][4];
#pragma unroll
    for (int f = 0; f < 2; ++f) {
        const f16* fp = fk + (size_t)(b * N + i0 + h * 32 + f * 16 + li) * FKD + lg * 8;
#pragma unroll
        for (int ks = 0; ks < 4; ++ks) fb[f][ks] = *(const f16x8*)(fp + ks * 32);
    }

    // K staging via global_load_lds: wave wv covers rows wv*8..wv*8+7, 2 instrs.
    // lane -> lds byte lane*16: row = base_row + lg, granule = li (linear).
    // global source granule = li ^ (row&7)  (inverse swizzle; row&7 = q*4+lg).
    {
#pragma unroll
        for (int q = 0; q < 2; ++q) {
            const int row = wv * 8 + q * 4 + lg;
            const f16* gsrc = fk + (size_t)(b * N + row) * FKD + CQ + (li ^ (q * 4 + lg)) * 8;
            __builtin_amdgcn_global_load_lds(AS1(gsrc), AS3(&kbuf[0][(wv * 8 + q * 4) * 128]), 16, 0, 0);
        }
    }

    const f16* vbase = v + (size_t)(b * C + c0 + li) * N + lg * 8;
    f32x4 oacc[4][2] = {};                       // [c-frag][i-frag(own half)]
    float ms[2] = {-1e30f, -1e30f}, ls[2] = {0.f, 0.f};
    __syncthreads();                             // prologue staging visible

    for (int t = 0; t < NT; ++t) {
        const f16* kc = &kbuf[t & 1][0];
        const int j0 = t * 128;
        // (a) stage next K tile (direct to LDS; drained by B1's implicit vmcnt(0))
        if (t < NT - 1) {
            const int jn = (t + 1) * 128;
#pragma unroll
            for (int q = 0; q < 2; ++q) {
                const int row = wv * 8 + q * 4 + lg;
                const f16* gsrc = fk + (size_t)(b * N + jn + row) * FKD + CQ + (li ^ (q * 4 + lg)) * 8;
                __builtin_amdgcn_global_load_lds(AS1(gsrc), AS3(&kbuf[(t + 1) & 1][(wv * 8 + q * 4) * 128]), 16, 0, 0);
            }
        }
        // (b) QK for own (j-slice, i-half): S^T = mfma(A=K, B=F)
        f16x8 kf4[4];
#pragma unroll
        for (int ks = 0; ks < 4; ++ks)
            kf4[ks] = *(const f16x8*)(&kc[(ws * 16 + li) * 128 + ((ks * 4 + lg) ^ swl) * 8]);
        f32x4 s[2] = {};
        __builtin_amdgcn_s_setprio(1);
#pragma unroll
        for (int ks = 0; ks < 4; ++ks) {
            s[0] = __builtin_amdgcn_mfma_f32_16x16x32_f16(kf4[ks], fb[0][ks], s[0], 0, 0, 0);
            s[1] = __builtin_amdgcn_mfma_f32_16x16x32_f16(kf4[ks], fb[1][ks], s[1], 0, 0, 0);
        }
        __builtin_amdgcn_s_setprio(0);
        // (c) slice-local max per query i=li
#pragma unroll
        for (int f = 0; f < 2; ++f) {
            float t0 = fmaxf(fmaxf(s[f][0], s[f][1]), fmaxf(s[f][2], s[f][3]));
            t0 = fmaxf(t0, __shfl_xor(t0, 16));
            t0 = fmaxf(t0, __shfl_xor(t0, 32));
            if (lane < 16) smax[h][ws][f][li] = t0;
        }
        // V prefetch, phase 0 (j0..j0+31)
        f16x8 vaA[4], vaB[4];
#pragma unroll
        for (int cf = 0; cf < 4; ++cf) vaA[cf] = *(const f16x8*)(vbase + (size_t)(cf * 16) * N + j0);
        __syncthreads();   // B1: smax visible (+ drains next-K gloads)
        // (d) combine max over 8 slices, own half
        float gm[2];
#pragma unroll
        for (int f = 0; f < 2; ++f) {
            float m0 = smax[h][0][f][li];
#pragma unroll
            for (int w = 1; w < 8; ++w) m0 = fmaxf(m0, smax[h][w][f][li]);
            gm[f] = m0;
        }
        // T13 deferred rescale (identical across waves of same half)
#pragma unroll
        for (int f = 0; f < 2; ++f) {
            if (!__all(gm[f] <= ms[f] + 8.0f)) {
                float mn = fmaxf(ms[f], gm[f]), sc = __expf(ms[f] - mn);
                ms[f] = mn; ls[f] *= sc;
#pragma unroll
                for (int cf = 0; cf < 4; ++cf) oacc[cf][f] *= sc;
            }
        }
        // (e) exp + P write (own rows), partial sums
        const int jl = ws * 16 + lg * 4;
        const int gg = (jl >> 3) ^ swl;
#pragma unroll
        for (int f = 0; f < 2; ++f) {
            f16x4 pk;
            float p0 = 0.f;
#pragma unroll
            for (int r = 0; r < 4; ++r) { float p = __expf(s[f][r] - ms[f]); p0 += p; pk[r] = (f16)p; }
            *(f16x4*)(&pbuf[(h * 32 + f * 16 + li) * 128 + gg * 8 + (jl & 7)]) = pk;
            p0 += __shfl_xor(p0, 16);
            p0 += __shfl_xor(p0, 32);
            if (lane < 16) ssum[h][ws][f][li] = p0;
        }
        // V prefetch, phase 1
#pragma unroll
        for (int cf = 0; cf < 4; ++cf) vaB[cf] = *(const f16x8*)(vbase + (size_t)(cf * 16) * N + j0 + 32);
        __syncthreads();   // B2: P + ssum visible (+ drains gloads)
        // (f) accumulate l over 8 slices, own half
#pragma unroll
        for (int f = 0; f < 2; ++f) {
            float a0 = 0.f;
#pragma unroll
            for (int w = 0; w < 8; ++w) a0 += ssum[h][w][f][li];
            ls[f] += a0;
        }
        // (g) PV: 4 phases over 128 j, own c-slice + i-half; rolling V prefetch
#pragma unroll
        for (int kf = 0; kf < 4; ++kf) {
            const int pg = (kf * 4 + lg) ^ swl;
            f16x8 pb0 = *(const f16x8*)(&pbuf[(h * 32 + li) * 128 + pg * 8]);
            f16x8 pb1 = *(const f16x8*)(&pbuf[(h * 32 + 16 + li) * 128 + pg * 8]);
            f16x8 vv0, vv1, vv2, vv3;
            if (kf & 1) { vv0 = vaB[0]; vv1 = vaB[1]; vv2 = vaB[2]; vv3 = vaB[3]; }
            else        { vv0 = vaA[0]; vv1 = vaA[1]; vv2 = vaA[2]; vv3 = vaA[3]; }
            if (kf < 2) {
#pragma unroll
                for (int cf = 0; cf < 4; ++cf) {
                    f16x8 nv = *(const f16x8*)(vbase + (size_t)(cf * 16) * N + j0 + (kf + 2) * 32);
                    if (kf & 1) vaB[cf] = nv; else vaA[cf] = nv;
                }
            }
            __builtin_amdgcn_s_setprio(1);
            oacc[0][0] = __builtin_amdgcn_mfma_f32_16x16x32_f16(vv0, pb0, oacc[0][0], 0, 0, 0);
            oacc[0][1] = __builtin_amdgcn_mfma_f32_16x16x32_f16(vv0, pb1, oacc[0][1], 0, 0, 0);
            oacc[1][0] = __builtin_amdgcn_mfma_f32_16x16x32_f16(vv1, pb0, oacc[1][0], 0, 0, 0);
            oacc[1][1] = __builtin_amdgcn_mfma_f32_16x16x32_f16(vv1, pb1, oacc[1][1], 0, 0, 0);
            oacc[2][0] = __builtin_amdgcn_mfma_f32_16x16x32_f16(vv2, pb0, oacc[2][0], 0, 0, 0);
            oacc[2][1] = __builtin_amdgcn_mfma_f32_16x16x32_f16(vv2, pb1, oacc[2][1], 0, 0, 0);
            oacc[3][0] = __builtin_amdgcn_mfma_f32_16x16x32_f16(vv3, pb0, oacc[3][0], 0, 0, 0);
            oacc[3][1] = __builtin_amdgcn_mfma_f32_16x16x32_f16(vv3, pb1, oacc[3][1], 0, 0, 0);
            __builtin_amdgcn_s_setprio(0);
        }
        // no 3rd barrier: next iter's B1 orders pbuf reuse; kbuf ordered by B2
    }

    // epilogue: O[c][i], i = i0 + h*32 + f*16 + li (coalesced over li); + residual
    const float alpha = alphap[0];
#pragma unroll
    for (int f = 0; f < 2; ++f) {
        const float invf = alpha / ls[f];
        const float* xp = x + (size_t)(b * C + c0) * N + i0 + h * 32 + f * 16 + li;
        float* op = out + (size_t)(b * C + c0) * N + i0 + h * 32 + f * 16 + li;
#pragma unroll
        for (int cf = 0; cf < 4; ++cf)
#pragma unroll
            for (int r = 0; r < 4; ++r) {
                const int cl = cf * 16 + lg * 4 + r;
                op[(size_t)cl * N] = oacc[cf][f][r] * invf + xp[(size_t)cl * N];
            }
    }
}

extern "C" void kernel_launch(void* const* d_in, const int* in_sizes, int n_in,
                              void* d_out, int out_size, void* d_ws, size_t ws_size,
                              hipStream_t stream) {
    const float* x     = (const float*)d_in[0];
    const float* Wf_w  = (const float*)d_in[1];
    const float* Wf_b  = (const float*)d_in[2];
    const float* Wh_w  = (const float*)d_in[3];
    const float* Wh_b  = (const float*)d_in[4];
    const float* Wl_w  = (const float*)d_in[5];
    const float* Wl_b  = (const float*)d_in[6];
    const float* alpha = (const float*)d_in[7];
    char* ws = (char*)d_ws;
    f16*   xt   = (f16*)(ws + WS_XT);
    f16*   fkb  = (f16*)(ws + WS_FK);
    f16*   vb   = (f16*)(ws + WS_V);
    f16*   wcat = (f16*)(ws + WS_WCAT);
    f16*   wl   = (f16*)(ws + WS_WL);
    float* bcat = (float*)(ws + WS_BC);
    float* out  = (float*)d_out;

    prep_weights<<<dim3((C * C + 255) / 256), dim3(256), 0, stream>>>(Wf_w, Wf_b, Wh_w, Wh_b, Wl_w, wcat, wl, bcat);
    transpose_x<<<dim3(BATCH * 8 * 64), dim3(256), 0, stream>>>(x, xt);
    proj_fk<<<dim3(256), dim3(256), 0, stream>>>(xt, wcat, bcat, fkb);
    proj_v<<<dim3(512), dim3(256), 0, stream>>>(xt, wl, Wl_b, vb);
    // 4 b x 64 query-tiles(64q) = 256 blocks x 16 waves = 1 block/CU, XCD-pinned
    attn<<<dim3(256), dim3(1024), 0, stream>>>(fkb, vb, x, alpha, out);
}

// Round 6
// 336.925 us; speedup vs baseline: 1.2845x; 1.2845x over previous
//
#include <hip/hip_runtime.h>
#include <hip/hip_bf16.h>

typedef _Float16 f16;
typedef _Float16 f16x4 __attribute__((ext_vector_type(4)));
typedef _Float16 f16x8 __attribute__((ext_vector_type(8)));
typedef float f32x4 __attribute__((ext_vector_type(4)));

constexpr int BATCH = 4, C = 512, CQ = 128, N = 4096;
constexpr int FKD = 256; // f(128) + k(128) channels, stacked

// workspace layout (bytes)
constexpr size_t WS_XT   = 0;                                      // f16 [B][N][C]   16 MB
constexpr size_t WS_FK   = WS_XT   + (size_t)BATCH * N * C * 2;    // f16 [B][N][256]  8 MB
constexpr size_t WS_V    = WS_FK   + (size_t)BATCH * N * FKD * 2;  // f16 [B][C][N]   16 MB
constexpr size_t WS_WCAT = WS_V    + (size_t)BATCH * C * N * 2;    // f16 [256][512]
constexpr size_t WS_WL   = WS_WCAT + (size_t)FKD * C * 2;          // f16 [512][512]
constexpr size_t WS_BC   = WS_WL   + (size_t)C * C * 2;            // f32 [256]

// ---------------------------------------------------------------- weights->fp16
__global__ void prep_weights(const float* __restrict__ Wf_w, const float* __restrict__ Wf_b,
                             const float* __restrict__ Wh_w, const float* __restrict__ Wh_b,
                             const float* __restrict__ Wl_w,
                             f16* __restrict__ wcat, f16* __restrict__ wl, float* __restrict__ bcat) {
    int i = blockIdx.x * 256 + threadIdx.x;                 // grid covers C*C
    if (i < FKD * C) {
        int o = i >> 9, c = i & 511;
        float v = (o < CQ) ? Wf_w[o * C + c] : Wh_w[(o - CQ) * C + c];
        wcat[i] = (f16)v;
    }
    if (i < C * C) wl[i] = (f16)Wl_w[i];
    if (i < FKD) bcat[i] = (i < CQ) ? Wf_b[i] : Wh_b[i - CQ];
}

// ---------------------------------------------------------------- x (B,C,N) f32 -> xT (B,N,C) f16
__global__ void transpose_x(const float* __restrict__ x, f16* __restrict__ xt) {
    __shared__ float tile[64][65];
    int gid = blockIdx.x;
    int b = gid >> 9, rem = gid & 511;
    int c0 = (rem >> 6) * 64, n0 = (rem & 63) * 64;
    int t = threadIdx.x;
    int tn = t & 63, tg = t >> 6;
    const float* xp = x + (size_t)b * C * N + (size_t)c0 * N + n0;
#pragma unroll
    for (int r = 0; r < 16; ++r) {
        int cl = tg + r * 4;
        tile[cl][tn] = xp[(size_t)cl * N + tn];
    }
    __syncthreads();
    f16* xo = xt + (size_t)b * N * C + (size_t)n0 * C + c0;
#pragma unroll
    for (int r = 0; r < 16; ++r) {
        int nl = tg + r * 4;
        xo[(size_t)nl * C + tn] = (f16)tile[tn][nl];
    }
}

// ---------------------------------------------------------------- FK projection (64n x 64o per wave)
__global__ void __launch_bounds__(256) proj_fk(const f16* __restrict__ xt, const f16* __restrict__ wcat,
                                               const float* __restrict__ bcat, f16* __restrict__ fk) {
    int wid = blockIdx.x * 4 + (threadIdx.x >> 6);   // 1024 waves: b(2) nt(6) ot(2)
    int lane = threadIdx.x & 63;
    int li = lane & 15, lg = lane >> 4;
    int b  = wid >> 8;
    int nt = (wid >> 2) & 63;
    int ot = wid & 3;
    int n0 = nt * 64, o0 = ot * 64;
    const f16* ap = xt + (size_t)(b * N + n0 + li) * C + lg * 8;
    const f16* bp = wcat + (size_t)(o0 + li) * C + lg * 8;
    f32x4 acc[4][4] = {};
    for (int ks = 0; ks < 16; ++ks) {
        f16x8 a4[4], b4[4];
#pragma unroll
        for (int t = 0; t < 4; ++t) a4[t] = *(const f16x8*)(ap + (size_t)(t * 16) * C + ks * 32);
#pragma unroll
        for (int t = 0; t < 4; ++t) b4[t] = *(const f16x8*)(bp + (size_t)(t * 16) * C + ks * 32);
#pragma unroll
        for (int tA = 0; tA < 4; ++tA)
#pragma unroll
            for (int tB = 0; tB < 4; ++tB)
                acc[tA][tB] = __builtin_amdgcn_mfma_f32_16x16x32_f16(a4[tA], b4[tB], acc[tA][tB], 0, 0, 0);
    }
#pragma unroll
    for (int tB = 0; tB < 4; ++tB) {
        int o = o0 + tB * 16 + li;
        float bias = bcat[o];
#pragma unroll
        for (int tA = 0; tA < 4; ++tA)
#pragma unroll
            for (int r = 0; r < 4; ++r) {
                int n = n0 + tA * 16 + lg * 4 + r;
                fk[(size_t)(b * N + n) * FKD + o] = (f16)(acc[tA][tB][r] + bias);
            }
    }
}

// ---------------------------------------------------------------- V projection (64c x 64n per wave)
__global__ void __launch_bounds__(256) proj_v(const f16* __restrict__ xt, const f16* __restrict__ wl,
                                              const float* __restrict__ wlb, f16* __restrict__ v) {
    int wid = blockIdx.x * 4 + (threadIdx.x >> 6);   // 2048 waves: b(2) ct(3) nt(6)
    int lane = threadIdx.x & 63;
    int li = lane & 15, lg = lane >> 4;
    int b  = wid >> 9;
    int ct = (wid >> 6) & 7;
    int nt = wid & 63;
    int c0 = ct * 64, n0 = nt * 64;
    const f16* ap = wl + (size_t)(c0 + li) * C + lg * 8;
    const f16* bp = xt + (size_t)(b * N + n0 + li) * C + lg * 8;
    f32x4 acc[4][4] = {};
    for (int ks = 0; ks < 16; ++ks) {
        f16x8 a4[4], b4[4];
#pragma unroll
        for (int t = 0; t < 4; ++t) a4[t] = *(const f16x8*)(ap + (size_t)(t * 16) * C + ks * 32);
#pragma unroll
        for (int t = 0; t < 4; ++t) b4[t] = *(const f16x8*)(bp + (size_t)(t * 16) * C + ks * 32);
#pragma unroll
        for (int tA = 0; tA < 4; ++tA)
#pragma unroll
            for (int tB = 0; tB < 4; ++tB)
                acc[tA][tB] = __builtin_amdgcn_mfma_f32_16x16x32_f16(a4[tA], b4[tB], acc[tA][tB], 0, 0, 0);
    }
#pragma unroll
    for (int tA = 0; tA < 4; ++tA)
#pragma unroll
        for (int r = 0; r < 4; ++r) {
            int c = c0 + tA * 16 + lg * 4 + r;
            float bias = wlb[c];
#pragma unroll
            for (int tB = 0; tB < 4; ++tB) {
                int n = n0 + tB * 16 + li;
                v[(size_t)(b * C + c) * N + n] = (f16)(acc[tA][tB][r] + bias);
            }
        }
}

// ---------------------------------------------------------------- flash attention + residual (v6)
// = v3 structure (8 waves, 32-query tile, 2 blocks/CU) with v4's fixes:
//   launch_bounds(512,2) -> 128-VGPR cap (second arg acts as min-BLOCKS/CU;
//   (512,4)/(1024,4) gave 64 VGPR and spill storms in v3/v5), and XCD
//   batch-pinning so each XCD's L2 holds ONE batch's K+V (~5 MB).
// Wave w: QK 16-j slice w, PV c-slice [w*64,w*64+64). P[32][128] f16 shared.
// K tile double-buffered (reg-staged, issue-early/write-late). 2 barriers/iter.
__global__ void __launch_bounds__(512, 2) attn(const f16* __restrict__ fk, const f16* __restrict__ v,
                                               const float* __restrict__ x, const float* __restrict__ alphap,
                                               float* __restrict__ out) {
    __shared__ __align__(16) f16 kbuf[2][128 * 128];   // 64 KB, double-buffered K tile
    __shared__ __align__(16) f16 pbuf[32 * 128];       // 8 KB shared P
    __shared__ float smax[8][2][16];
    __shared__ float ssum[8][2][16];

    const int tid  = threadIdx.x;
    const int wv   = tid >> 6;
    const int lane = tid & 63;
    const int li = lane & 15, lg = lane >> 4;
    const int swl = li & 7;
    // XCD-pinning: 512 blocks, blk%8 round-robin -> XCD x serves batch x>>1
    const int v0 = blockIdx.x;
    const int b  = (v0 & 7) >> 1;
    const int it = ((v0 & 1) << 6) | (v0 >> 3);   // 0..127, bijective per batch
    const int i0 = it * 32;
    const int c0 = wv * 64;

    // F fragments (B operand of swapped QK): col=i, k=ck; 2 i-frags
    f16x8 fb[2][4];
#pragma unroll
    for (int f = 0; f < 2; ++f) {
        const f16* fp = fk + (size_t)(b * N + i0 + f * 16 + li) * FKD + lg * 8;
#pragma unroll
        for (int ks = 0; ks < 4; ++ks) fb[f][ks] = *(const f16x8*)(fp + ks * 32);
    }

    // staging geometry: 512 thr x 64B = 32KB tile; row = tid>>2, 4 granules each
    const int sr  = tid >> 2;
    const int sg  = (tid & 3) * 4;
    const int ssw = sr & 7;
    {   // prologue: stage tile 0 -> kbuf[0]
        const f16* src = fk + (size_t)(b * N + sr) * FKD + CQ + (tid & 3) * 32;
#pragma unroll
        for (int k = 0; k < 4; ++k) {
            f16x8 vv = *(const f16x8*)(src + k * 8);
            *(f16x8*)(&kbuf[0][sr * 128 + ((sg + k) ^ ssw) * 8]) = vv;
        }
    }

    const f16* vbase = v + (size_t)(b * C + c0 + li) * N + lg * 8;
    f32x4 oacc[4][2] = {};                       // [c-frag][i-frag]
    float ms[2] = {-1e30f, -1e30f};
    float ls[2] = {0.f, 0.f};
    __syncthreads();

    for (int t = 0; t < 32; ++t) {
        const f16* kc = &kbuf[t & 1][0];
        f16*       kn = &kbuf[(t + 1) & 1][0];
        const int j0 = t * 128;
        // (a) issue next K-tile global loads early (T14 issue-early/write-late)
        const int jn = (t < 31) ? (t + 1) * 128 : 0;
        const f16* ssrc = fk + (size_t)(b * N + jn + sr) * FKD + CQ + (tid & 3) * 32;
        f16x8 stg[4];
#pragma unroll
        for (int k = 0; k < 4; ++k) stg[k] = *(const f16x8*)(ssrc + k * 8);

        // (b) QK for this wave's 16-j slice, both i-frags
        f16x8 kf4[4];
#pragma unroll
        for (int ks = 0; ks < 4; ++ks)
            kf4[ks] = *(const f16x8*)(&kc[(wv * 16 + li) * 128 + ((ks * 4 + lg) ^ swl) * 8]);
        f32x4 s[2] = {};
        __builtin_amdgcn_s_setprio(1);
#pragma unroll
        for (int ks = 0; ks < 4; ++ks) {
            s[0] = __builtin_amdgcn_mfma_f32_16x16x32_f16(kf4[ks], fb[0][ks], s[0], 0, 0, 0);
            s[1] = __builtin_amdgcn_mfma_f32_16x16x32_f16(kf4[ks], fb[1][ks], s[1], 0, 0, 0);
        }
        __builtin_amdgcn_s_setprio(0);

        // (c) wave-local max per query (rows j = wv*16 + lg*4 + r)
#pragma unroll
        for (int f = 0; f < 2; ++f) {
            float t0 = fmaxf(fmaxf(s[f][0], s[f][1]), fmaxf(s[f][2], s[f][3]));
            t0 = fmaxf(t0, __shfl_xor(t0, 16));
            t0 = fmaxf(t0, __shfl_xor(t0, 32));
            if (lane < 16) smax[wv][f][li] = t0;
        }
        // V prefetch for PV kf=0, issued before the barrier
        f16x8 va[2][4];
#pragma unroll
        for (int cf = 0; cf < 4; ++cf) va[0][cf] = *(const f16x8*)(vbase + (size_t)(cf * 16) * N + j0);
        __syncthreads();   // B1: max stats visible
        // (d) tile max over 8 waves (broadcast reads)
        float gm[2];
#pragma unroll
        for (int f = 0; f < 2; ++f) {
            float m0 = smax[0][f][li];
#pragma unroll
            for (int w = 1; w < 8; ++w) m0 = fmaxf(m0, smax[w][f][li]);
            gm[f] = m0;
        }
        // V prefetch for kf=1
#pragma unroll
        for (int cf = 0; cf < 4; ++cf) va[1][cf] = *(const f16x8*)(vbase + (size_t)(cf * 16) * N + j0 + 32);
        // T13 deferred rescale (identical decision in all waves: shared stats)
#pragma unroll
        for (int f = 0; f < 2; ++f) {
            if (!__all(gm[f] <= ms[f] + 8.0f)) {
                float mn = fmaxf(ms[f], gm[f]), sc = __expf(ms[f] - mn);
                ms[f] = mn; ls[f] *= sc;
#pragma unroll
                for (int cf = 0; cf < 4; ++cf) oacc[cf][f] *= sc;
            }
        }
        // (e) exp (this wave's 4 j per lane per f) + P write + partial sums
        const int jl = wv * 16 + lg * 4;
        const int gg = (jl >> 3) ^ swl;
#pragma unroll
        for (int f = 0; f < 2; ++f) {
            f16x4 pk;
            float p0 = 0.f;
#pragma unroll
            for (int r = 0; r < 4; ++r) { float p = __expf(s[f][r] - ms[f]); p0 += p; pk[r] = (f16)p; }
            *(f16x4*)(&pbuf[(f * 16 + li) * 128 + gg * 8 + (jl & 7)]) = pk;
            p0 += __shfl_xor(p0, 16);
            p0 += __shfl_xor(p0, 32);
            if (lane < 16) ssum[wv][f][li] = p0;
        }
        // write staged K tile to next buffer (loads from (a) drained by now)
#pragma unroll
        for (int k = 0; k < 4; ++k)
            *(f16x8*)(&kn[sr * 128 + ((sg + k) ^ ssw) * 8]) = stg[k];
        __syncthreads();   // B2: P + ssum + next-K visible
        // (f) accumulate l from shared partial sums
#pragma unroll
        for (int f = 0; f < 2; ++f) {
            float a0 = 0.f;
#pragma unroll
            for (int w = 0; w < 8; ++w) a0 += ssum[w][f][li];
            ls[f] += a0;
        }
        // (g) PV over full 128 j, this wave's 64 channels; rolling V prefetch
#pragma unroll
        for (int kf = 0; kf < 4; ++kf) {
            const int cur = kf & 1;
            const int pg = (kf * 4 + lg) ^ swl;
            f16x8 pb0 = *(const f16x8*)(&pbuf[li * 128 + pg * 8]);
            f16x8 pb1 = *(const f16x8*)(&pbuf[(16 + li) * 128 + pg * 8]);
            f16x8 vv0 = va[cur][0], vv1 = va[cur][1], vv2 = va[cur][2], vv3 = va[cur][3];
            if (kf < 2) {
#pragma unroll
                for (int cf = 0; cf < 4; ++cf)
                    va[cur][cf] = *(const f16x8*)(vbase + (size_t)(cf * 16) * N + j0 + (kf + 2) * 32);
            }
            __builtin_amdgcn_s_setprio(1);
            oacc[0][0] = __builtin_amdgcn_mfma_f32_16x16x32_f16(vv0, pb0, oacc[0][0], 0, 0, 0);
            oacc[0][1] = __builtin_amdgcn_mfma_f32_16x16x32_f16(vv0, pb1, oacc[0][1], 0, 0, 0);
            oacc[1][0] = __builtin_amdgcn_mfma_f32_16x16x32_f16(vv1, pb0, oacc[1][0], 0, 0, 0);
            oacc[1][1] = __builtin_amdgcn_mfma_f32_16x16x32_f16(vv1, pb1, oacc[1][1], 0, 0, 0);
            oacc[2][0] = __builtin_amdgcn_mfma_f32_16x16x32_f16(vv2, pb0, oacc[2][0], 0, 0, 0);
            oacc[2][1] = __builtin_amdgcn_mfma_f32_16x16x32_f16(vv2, pb1, oacc[2][1], 0, 0, 0);
            oacc[3][0] = __builtin_amdgcn_mfma_f32_16x16x32_f16(vv3, pb0, oacc[3][0], 0, 0, 0);
            oacc[3][1] = __builtin_amdgcn_mfma_f32_16x16x32_f16(vv3, pb1, oacc[3][1], 0, 0, 0);
            __builtin_amdgcn_s_setprio(0);
        }
        // no 3rd barrier: next iter's B1 orders pbuf/kbuf reuse
    }

    // epilogue: O[c][i], i coalesced over li; + residual
    const float alpha = alphap[0];
#pragma unroll
    for (int f = 0; f < 2; ++f) {
        const float invf = alpha / ls[f];
        const float* xp = x + (size_t)(b * C + c0) * N + i0 + f * 16 + li;
        float* op = out + (size_t)(b * C + c0) * N + i0 + f * 16 + li;
#pragma unroll
        for (int cf = 0; cf < 4; ++cf)
#pragma unroll
            for (int r = 0; r < 4; ++r) {
                const int cl = cf * 16 + lg * 4 + r;
                op[(size_t)cl * N] = oacc[cf][f][r] * invf + xp[(size_t)cl * N];
            }
    }
}

extern "C" void kernel_launch(void* const* d_in, const int* in_sizes, int n_in,
                              void* d_out, int out_size, void* d_ws, size_t ws_size,
                              hipStream_t stream) {
    const float* x     = (const float*)d_in[0];
    const float* Wf_w  = (const float*)d_in[1];
    const float* Wf_b  = (const float*)d_in[2];
    const float* Wh_w  = (const float*)d_in[3];
    const float* Wh_b  = (const float*)d_in[4];
    const float* Wl_w  = (const float*)d_in[5];
    const float* Wl_b  = (const float*)d_in[6];
    const float* alpha = (const float*)d_in[7];
    char* ws = (char*)d_ws;
    f16*   xt   = (f16*)(ws + WS_XT);
    f16*   fkb  = (f16*)(ws + WS_FK);
    f16*   vb   = (f16*)(ws + WS_V);
    f16*   wcat = (f16*)(ws + WS_WCAT);
    f16*   wl   = (f16*)(ws + WS_WL);
    float* bcat = (float*)(ws + WS_BC);
    float* out  = (float*)d_out;

    prep_weights<<<dim3((C * C + 255) / 256), dim3(256), 0, stream>>>(Wf_w, Wf_b, Wh_w, Wh_b, Wl_w, wcat, wl, bcat);
    transpose_x<<<dim3(BATCH * 8 * 64), dim3(256), 0, stream>>>(x, xt);
    proj_fk<<<dim3(256), dim3(256), 0, stream>>>(xt, wcat, bcat, fkb);
    proj_v<<<dim3(512), dim3(256), 0, stream>>>(xt, wl, Wl_b, vb);
    // 4 b x 128 query-tiles(32q) = 512 blocks x 8 waves; 2 blocks/CU, XCD-pinned
    attn<<<dim3(512), dim3(512), 0, stream>>>(fkb, vb, x, alpha, out);
}

// Round 7
// 271.831 us; speedup vs baseline: 1.5921x; 1.2395x over previous
//
#include <hip/hip_runtime.h>
#include <hip/hip_bf16.h>

typedef _Float16 f16;
typedef _Float16 f16x4 __attribute__((ext_vector_type(4)));
typedef _Float16 f16x8 __attribute__((ext_vector_type(8)));
typedef float f32x4 __attribute__((ext_vector_type(4)));

constexpr int BATCH = 4, C = 512, CQ = 128, N = 4096;
constexpr int FKD = 256; // f(128) + k(128) channels, stacked

// workspace layout (bytes)
constexpr size_t WS_XT   = 0;                                      // f16 [B][N][C]   16 MB
constexpr size_t WS_FK   = WS_XT   + (size_t)BATCH * N * C * 2;    // f16 [B][N][256]  8 MB
constexpr size_t WS_V    = WS_FK   + (size_t)BATCH * N * FKD * 2;  // f16 [B][C][N]   16 MB
constexpr size_t WS_WCAT = WS_V    + (size_t)BATCH * C * N * 2;    // f16 [256][512]
constexpr size_t WS_WL   = WS_WCAT + (size_t)FKD * C * 2;          // f16 [512][512]
constexpr size_t WS_BC   = WS_WL   + (size_t)C * C * 2;            // f32 [256]

#define AS1(p) ((const __attribute__((address_space(1))) void*)(p))
#define AS3(p) ((__attribute__((address_space(3))) void*)(p))

// ---------------------------------------------------------------- weights->fp16
__global__ void prep_weights(const float* __restrict__ Wf_w, const float* __restrict__ Wf_b,
                             const float* __restrict__ Wh_w, const float* __restrict__ Wh_b,
                             const float* __restrict__ Wl_w,
                             f16* __restrict__ wcat, f16* __restrict__ wl, float* __restrict__ bcat) {
    int i = blockIdx.x * 256 + threadIdx.x;                 // grid covers C*C
    if (i < FKD * C) {
        int o = i >> 9, c = i & 511;
        float v = (o < CQ) ? Wf_w[o * C + c] : Wh_w[(o - CQ) * C + c];
        wcat[i] = (f16)v;
    }
    if (i < C * C) wl[i] = (f16)Wl_w[i];
    if (i < FKD) bcat[i] = (i < CQ) ? Wf_b[i] : Wh_b[i - CQ];
}

// ---------------------------------------------------------------- x (B,C,N) f32 -> xT (B,N,C) f16
__global__ void transpose_x(const float* __restrict__ x, f16* __restrict__ xt) {
    __shared__ float tile[64][65];
    int gid = blockIdx.x;
    int b = gid >> 9, rem = gid & 511;
    int c0 = (rem >> 6) * 64, n0 = (rem & 63) * 64;
    int t = threadIdx.x;
    int tn = t & 63, tg = t >> 6;
    const float* xp = x + (size_t)b * C * N + (size_t)c0 * N + n0;
#pragma unroll
    for (int r = 0; r < 16; ++r) {
        int cl = tg + r * 4;
        tile[cl][tn] = xp[(size_t)cl * N + tn];
    }
    __syncthreads();
    f16* xo = xt + (size_t)b * N * C + (size_t)n0 * C + c0;
#pragma unroll
    for (int r = 0; r < 16; ++r) {
        int nl = tg + r * 4;
        xo[(size_t)nl * C + tn] = (f16)tile[tn][nl];
    }
}

// ---------------------------------------------------------------- FK projection (64n x 64o per wave)
__global__ void __launch_bounds__(256) proj_fk(const f16* __restrict__ xt, const f16* __restrict__ wcat,
                                               const float* __restrict__ bcat, f16* __restrict__ fk) {
    int wid = blockIdx.x * 4 + (threadIdx.x >> 6);   // 1024 waves: b(2) nt(6) ot(2)
    int lane = threadIdx.x & 63;
    int li = lane & 15, lg = lane >> 4;
    int b  = wid >> 8;
    int nt = (wid >> 2) & 63;
    int ot = wid & 3;
    int n0 = nt * 64, o0 = ot * 64;
    const f16* ap = xt + (size_t)(b * N + n0 + li) * C + lg * 8;
    const f16* bp = wcat + (size_t)(o0 + li) * C + lg * 8;
    f32x4 acc[4][4] = {};
    for (int ks = 0; ks < 16; ++ks) {
        f16x8 a4[4], b4[4];
#pragma unroll
        for (int t = 0; t < 4; ++t) a4[t] = *(const f16x8*)(ap + (size_t)(t * 16) * C + ks * 32);
#pragma unroll
        for (int t = 0; t < 4; ++t) b4[t] = *(const f16x8*)(bp + (size_t)(t * 16) * C + ks * 32);
#pragma unroll
        for (int tA = 0; tA < 4; ++tA)
#pragma unroll
            for (int tB = 0; tB < 4; ++tB)
                acc[tA][tB] = __builtin_amdgcn_mfma_f32_16x16x32_f16(a4[tA], b4[tB], acc[tA][tB], 0, 0, 0);
    }
#pragma unroll
    for (int tB = 0; tB < 4; ++tB) {
        int o = o0 + tB * 16 + li;
        float bias = bcat[o];
#pragma unroll
        for (int tA = 0; tA < 4; ++tA)
#pragma unroll
            for (int r = 0; r < 4; ++r) {
                int n = n0 + tA * 16 + lg * 4 + r;
                fk[(size_t)(b * N + n) * FKD + o] = (f16)(acc[tA][tB][r] + bias);
            }
    }
}

// ---------------------------------------------------------------- V projection (64c x 64n per wave)
__global__ void __launch_bounds__(256) proj_v(const f16* __restrict__ xt, const f16* __restrict__ wl,
                                              const float* __restrict__ wlb, f16* __restrict__ v) {
    int wid = blockIdx.x * 4 + (threadIdx.x >> 6);   // 2048 waves: b(2) ct(3) nt(6)
    int lane = threadIdx.x & 63;
    int li = lane & 15, lg = lane >> 4;
    int b  = wid >> 9;
    int ct = (wid >> 6) & 7;
    int nt = wid & 63;
    int c0 = ct * 64, n0 = nt * 64;
    const f16* ap = wl + (size_t)(c0 + li) * C + lg * 8;
    const f16* bp = xt + (size_t)(b * N + n0 + li) * C + lg * 8;
    f32x4 acc[4][4] = {};
    for (int ks = 0; ks < 16; ++ks) {
        f16x8 a4[4], b4[4];
#pragma unroll
        for (int t = 0; t < 4; ++t) a4[t] = *(const f16x8*)(ap + (size_t)(t * 16) * C + ks * 32);
#pragma unroll
        for (int t = 0; t < 4; ++t) b4[t] = *(const f16x8*)(bp + (size_t)(t * 16) * C + ks * 32);
#pragma unroll
        for (int tA = 0; tA < 4; ++tA)
#pragma unroll
            for (int tB = 0; tB < 4; ++tB)
                acc[tA][tB] = __builtin_amdgcn_mfma_f32_16x16x32_f16(a4[tA], b4[tB], acc[tA][tB], 0, 0, 0);
    }
#pragma unroll
    for (int tA = 0; tA < 4; ++tA)
#pragma unroll
        for (int r = 0; r < 4; ++r) {
            int c = c0 + tA * 16 + lg * 4 + r;
            float bias = wlb[c];
#pragma unroll
            for (int tB = 0; tB < 4; ++tB) {
                int n = n0 + tB * 16 + li;
                v[(size_t)(b * C + c) * N + n] = (f16)(acc[tA][tB][r] + bias);
            }
        }
}

// ---------------------------------------------------------------- flash attention + residual (v7)
// v4 geometry (256 blocks, 8 waves, 64q tile, XCD-pinned) + software pipeline:
//   per iter t: [stats(t) | exp+Pwrite(t)] B2 [gld_lds K(t+2)] [PV(t) ∥ QK(t+1)] B1
// K staged DIRECT to LDS with inverse-swizzled global source (rule 21); the
// gld_lds for tile t+2 drains at the NEXT B2 -> one full iteration in flight.
// pbuf single-buffered: reads at PV(t) complete before B1(t); writes at b(t+1) after.
__global__ void __launch_bounds__(512, 2) attn(const f16* __restrict__ fk, const f16* __restrict__ v,
                                               const float* __restrict__ x, const float* __restrict__ alphap,
                                               float* __restrict__ out) {
    __shared__ __align__(16) f16 kbuf[2][128 * 128];   // 64 KB, double-buffered K tile
    __shared__ __align__(16) f16 pbuf[64 * 128];       // 16 KB shared P
    __shared__ float smax[8][4][16];
    __shared__ float ssum[8][4][16];

    const int tid  = threadIdx.x;
    const int wv   = tid >> 6;
    const int lane = tid & 63;
    const int li = lane & 15, lg = lane >> 4;
    const int swl = li & 7;
    // XCD-pinning: under blk%8 round-robin, each XCD sees a single batch
    const int v0 = blockIdx.x;
    const int b  = (v0 & 7) >> 1;
    const int it = ((v0 & 1) << 5) | (v0 >> 3);
    const int i0 = it * 64;
    const int c0 = wv * 64;

    // F fragments (B operand of swapped QK): col=i, k=ck; 4 i-frags
    f16x8 fb[4][4];
#pragma unroll
    for (int f = 0; f < 4; ++f) {
        const f16* fp = fk + (size_t)(b * N + i0 + f * 16 + li) * FKD + lg * 8;
#pragma unroll
        for (int ks = 0; ks < 4; ++ks) fb[f][ks] = *(const f16x8*)(fp + ks * 32);
    }

    // K staging via global_load_lds: wave wv stages rows [wv*16, wv*16+16), 4 instrs.
    // LDS dest linear (lane L -> row_local L>>4, granule L&15); global source
    // granule pre-inverse-swizzled: li ^ (row&7), row&7 = (q*4+lg)&7.
    auto STAGE = [&](int tile, int buf) {
#pragma unroll
        for (int q = 0; q < 4; ++q) {
            const int row = wv * 16 + q * 4 + lg;
            const f16* gsrc = fk + (size_t)(b * N + tile * 128 + row) * FKD + CQ + (li ^ ((q * 4 + lg) & 7)) * 8;
            __builtin_amdgcn_global_load_lds(AS1(gsrc), AS3(&kbuf[buf][(wv * 16 + q * 4) * 128]), 16, 0, 0);
        }
    };

    f32x4 s[4];
    auto QK = [&](int tile) {   // S^T = mfma(A=K, B=F) for this wave's 16-j slice
        const f16* kc = &kbuf[tile & 1][0];
        f16x8 kf4[4];
#pragma unroll
        for (int ks = 0; ks < 4; ++ks)
            kf4[ks] = *(const f16x8*)(&kc[(wv * 16 + li) * 128 + ((ks * 4 + lg) ^ swl) * 8]);
#pragma unroll
        for (int f = 0; f < 4; ++f) s[f] = (f32x4){0.f, 0.f, 0.f, 0.f};
        __builtin_amdgcn_s_setprio(1);
#pragma unroll
        for (int ks = 0; ks < 4; ++ks)
#pragma unroll
            for (int f = 0; f < 4; ++f)
                s[f] = __builtin_amdgcn_mfma_f32_16x16x32_f16(kf4[ks], fb[f][ks], s[f], 0, 0, 0);
        __builtin_amdgcn_s_setprio(0);
    };
    auto SMAXW = [&]() {        // wave-local max per query -> smax
#pragma unroll
        for (int f = 0; f < 4; ++f) {
            float t0 = fmaxf(fmaxf(s[f][0], s[f][1]), fmaxf(s[f][2], s[f][3]));
            t0 = fmaxf(t0, __shfl_xor(t0, 16));
            t0 = fmaxf(t0, __shfl_xor(t0, 32));
            if (lane < 16) smax[wv][f][li] = t0;
        }
    };

    // prologue: stage tiles 0,1; QK(0); publish smax(0)
    STAGE(0, 0);
    STAGE(1, 1);
    __syncthreads();           // drains prologue gld_lds
    QK(0);
    SMAXW();
    __syncthreads();           // B1(-1): smax(0) visible

    const f16* vbase = v + (size_t)(b * C + c0 + li) * N + lg * 8;
    f32x4 oacc[4][4] = {};                       // [c-frag][i-frag]
    float ms[4] = {-1e30f, -1e30f, -1e30f, -1e30f};
    float ls[4] = {0.f, 0.f, 0.f, 0.f};

    for (int t = 0; t < 32; ++t) {
        const int j0 = t * 128;
        // (a) V prefetch phase 0 + global stats + T13 rescale
        f16x8 va0[4], va1[4];
#pragma unroll
        for (int cf = 0; cf < 4; ++cf) va0[cf] = *(const f16x8*)(vbase + (size_t)(cf * 16) * N + j0);
        float gm[4];
#pragma unroll
        for (int f = 0; f < 4; ++f) {
            float m0 = smax[0][f][li];
#pragma unroll
            for (int w = 1; w < 8; ++w) m0 = fmaxf(m0, smax[w][f][li]);
            gm[f] = m0;
        }
#pragma unroll
        for (int f = 0; f < 4; ++f) {
            if (!__all(gm[f] <= ms[f] + 8.0f)) {
                float mn = fmaxf(ms[f], gm[f]), sc = __expf(ms[f] - mn);
                ms[f] = mn; ls[f] *= sc;
#pragma unroll
                for (int cf = 0; cf < 4; ++cf) oacc[cf][f] *= sc;
            }
        }
        // (b) exp + P write (this wave's 4 j per lane per f) + partial sums
        const int jl = wv * 16 + lg * 4;
        const int gg = (jl >> 3) ^ swl;
#pragma unroll
        for (int f = 0; f < 4; ++f) {
            f16x4 pk;
            float p0 = 0.f;
#pragma unroll
            for (int r = 0; r < 4; ++r) { float p = __expf(s[f][r] - ms[f]); p0 += p; pk[r] = (f16)p; }
            *(f16x4*)(&pbuf[(f * 16 + li) * 128 + gg * 8 + (jl & 7)]) = pk;
            p0 += __shfl_xor(p0, 16);
            p0 += __shfl_xor(p0, 32);
            if (lane < 16) ssum[wv][f][li] = p0;
        }
        __syncthreads();   // B2(t): P+ssum visible; drains K(t+1) gld_lds from iter t-1
        // (c) stage K(t+2) -> kbuf[t&1] (in flight until B2(t+1))
        if (t < 30) STAGE(t + 2, t & 1);
        // (e) accumulate l from shared partial sums
#pragma unroll
        for (int f = 0; f < 4; ++f) {
            float a0 = 0.f;
#pragma unroll
            for (int w = 0; w < 8; ++w) a0 += ssum[w][f][li];
            ls[f] += a0;
        }
        // (f) PV(t) over 128 j interleaved with QK(t+1); rolling V prefetch
#pragma unroll
        for (int cf = 0; cf < 4; ++cf) va1[cf] = *(const f16x8*)(vbase + (size_t)(cf * 16) * N + j0 + 32);
#define PVPHASE(KF, VA)                                                                     \
        {                                                                                   \
            const int pg = ((KF) * 4 + lg) ^ swl;                                           \
            f16x8 pb[4];                                                                    \
            _Pragma("unroll")                                                               \
            for (int f = 0; f < 4; ++f) pb[f] = *(const f16x8*)(&pbuf[(f * 16 + li) * 128 + pg * 8]); \
            __builtin_amdgcn_s_setprio(1);                                                  \
            _Pragma("unroll")                                                               \
            for (int f = 0; f < 4; ++f) {                                                   \
                oacc[0][f] = __builtin_amdgcn_mfma_f32_16x16x32_f16(VA[0], pb[f], oacc[0][f], 0, 0, 0); \
                oacc[1][f] = __builtin_amdgcn_mfma_f32_16x16x32_f16(VA[1], pb[f], oacc[1][f], 0, 0, 0); \
                oacc[2][f] = __builtin_amdgcn_mfma_f32_16x16x32_f16(VA[2], pb[f], oacc[2][f], 0, 0, 0); \
                oacc[3][f] = __builtin_amdgcn_mfma_f32_16x16x32_f16(VA[3], pb[f], oacc[3][f], 0, 0, 0); \
            }                                                                               \
            __builtin_amdgcn_s_setprio(0);                                                  \
        }
        PVPHASE(0, va0);
#pragma unroll
        for (int cf = 0; cf < 4; ++cf) va0[cf] = *(const f16x8*)(vbase + (size_t)(cf * 16) * N + j0 + 64);
        PVPHASE(1, va1);
#pragma unroll
        for (int cf = 0; cf < 4; ++cf) va1[cf] = *(const f16x8*)(vbase + (size_t)(cf * 16) * N + j0 + 96);
        if (t < 31) QK(t + 1);           // fills s[] for next iteration
        PVPHASE(2, va0);
        PVPHASE(3, va1);
        // (g,h) publish smax(t+1)
        if (t < 31) {
            SMAXW();
            __syncthreads();   // B1(t): smax visible; separates pbuf reads from next writes
        }
    }

    // epilogue: O[c][i], i coalesced over li; + residual
    const float alpha = alphap[0];
#pragma unroll
    for (int f = 0; f < 4; ++f) {
        const float invf = alpha / ls[f];
        const float* xp = x + (size_t)(b * C + c0) * N + i0 + f * 16 + li;
        float* op = out + (size_t)(b * C + c0) * N + i0 + f * 16 + li;
#pragma unroll
        for (int cf = 0; cf < 4; ++cf)
#pragma unroll
            for (int r = 0; r < 4; ++r) {
                const int cl = cf * 16 + lg * 4 + r;
                op[(size_t)cl * N] = oacc[cf][f][r] * invf + xp[(size_t)cl * N];
            }
    }
}

extern "C" void kernel_launch(void* const* d_in, const int* in_sizes, int n_in,
                              void* d_out, int out_size, void* d_ws, size_t ws_size,
                              hipStream_t stream) {
    const float* x     = (const float*)d_in[0];
    const float* Wf_w  = (const float*)d_in[1];
    const float* Wf_b  = (const float*)d_in[2];
    const float* Wh_w  = (const float*)d_in[3];
    const float* Wh_b  = (const float*)d_in[4];
    const float* Wl_w  = (const float*)d_in[5];
    const float* Wl_b  = (const float*)d_in[6];
    const float* alpha = (const float*)d_in[7];
    char* ws = (char*)d_ws;
    f16*   xt   = (f16*)(ws + WS_XT);
    f16*   fkb  = (f16*)(ws + WS_FK);
    f16*   vb   = (f16*)(ws + WS_V);
    f16*   wcat = (f16*)(ws + WS_WCAT);
    f16*   wl   = (f16*)(ws + WS_WL);
    float* bcat = (float*)(ws + WS_BC);
    float* out  = (float*)d_out;

    prep_weights<<<dim3((C * C + 255) / 256), dim3(256), 0, stream>>>(Wf_w, Wf_b, Wh_w, Wh_b, Wl_w, wcat, wl, bcat);
    transpose_x<<<dim3(BATCH * 8 * 64), dim3(256), 0, stream>>>(x, xt);
    proj_fk<<<dim3(256), dim3(256), 0, stream>>>(xt, wcat, bcat, fkb);
    proj_v<<<dim3(512), dim3(256), 0, stream>>>(xt, wl, Wl_b, vb);
    // 4 b x 64 query-tiles(64q) = 256 blocks x 8 waves = 1 block/CU, XCD-pinned
    attn<<<dim3(256), dim3(512), 0, stream>>>(fkb, vb, x, alpha, out);
}

// Round 8
// 246.023 us; speedup vs baseline: 1.7591x; 1.1049x over previous
//
#include <hip/hip_runtime.h>
#include <hip/hip_bf16.h>

typedef _Float16 f16;
typedef _Float16 f16x4 __attribute__((ext_vector_type(4)));
typedef _Float16 f16x8 __attribute__((ext_vector_type(8)));
typedef float f32x4 __attribute__((ext_vector_type(4)));

constexpr int BATCH = 4, C = 512, CQ = 128, N = 4096;
constexpr int FKD = 256; // f(128) + k(128) channels, stacked

// workspace layout (bytes)
constexpr size_t WS_XT   = 0;                                      // f16 [B][N][C]   16 MB
constexpr size_t WS_FK   = WS_XT   + (size_t)BATCH * N * C * 2;    // f16 [B][N][256]  8 MB
constexpr size_t WS_V    = WS_FK   + (size_t)BATCH * N * FKD * 2;  // f16 [B][C][N]   16 MB
constexpr size_t WS_WCAT = WS_V    + (size_t)BATCH * C * N * 2;    // f16 [256][512]
constexpr size_t WS_WL   = WS_WCAT + (size_t)FKD * C * 2;          // f16 [512][512]
constexpr size_t WS_BC   = WS_WL   + (size_t)C * C * 2;            // f32 [256]

#define AS1(p) ((const __attribute__((address_space(1))) void*)(p))
#define AS3(p) ((__attribute__((address_space(3))) void*)(p))

// ---------------------------------------------------------------- weights->fp16
__global__ void prep_weights(const float* __restrict__ Wf_w, const float* __restrict__ Wf_b,
                             const float* __restrict__ Wh_w, const float* __restrict__ Wh_b,
                             const float* __restrict__ Wl_w,
                             f16* __restrict__ wcat, f16* __restrict__ wl, float* __restrict__ bcat) {
    int i = blockIdx.x * 256 + threadIdx.x;                 // grid covers C*C
    if (i < FKD * C) {
        int o = i >> 9, c = i & 511;
        float v = (o < CQ) ? Wf_w[o * C + c] : Wh_w[(o - CQ) * C + c];
        wcat[i] = (f16)v;
    }
    if (i < C * C) wl[i] = (f16)Wl_w[i];
    if (i < FKD) bcat[i] = (i < CQ) ? Wf_b[i] : Wh_b[i - CQ];
}

// ---------------------------------------------------------------- x (B,C,N) f32 -> xT (B,N,C) f16
__global__ void transpose_x(const float* __restrict__ x, f16* __restrict__ xt) {
    __shared__ float tile[64][65];
    int gid = blockIdx.x;
    int b = gid >> 9, rem = gid & 511;
    int c0 = (rem >> 6) * 64, n0 = (rem & 63) * 64;
    int t = threadIdx.x;
    int tn = t & 63, tg = t >> 6;
    const float* xp = x + (size_t)b * C * N + (size_t)c0 * N + n0;
#pragma unroll
    for (int r = 0; r < 16; ++r) {
        int cl = tg + r * 4;
        tile[cl][tn] = xp[(size_t)cl * N + tn];
    }
    __syncthreads();
    f16* xo = xt + (size_t)b * N * C + (size_t)n0 * C + c0;
#pragma unroll
    for (int r = 0; r < 16; ++r) {
        int nl = tg + r * 4;
        xo[(size_t)nl * C + tn] = (f16)tile[tn][nl];
    }
}

// ---------------------------------------------------------------- FK projection (64n x 64o per wave)
__global__ void __launch_bounds__(256) proj_fk(const f16* __restrict__ xt, const f16* __restrict__ wcat,
                                               const float* __restrict__ bcat, f16* __restrict__ fk) {
    int wid = blockIdx.x * 4 + (threadIdx.x >> 6);   // 1024 waves: b(2) nt(6) ot(2)
    int lane = threadIdx.x & 63;
    int li = lane & 15, lg = lane >> 4;
    int b  = wid >> 8;
    int nt = (wid >> 2) & 63;
    int ot = wid & 3;
    int n0 = nt * 64, o0 = ot * 64;
    const f16* ap = xt + (size_t)(b * N + n0 + li) * C + lg * 8;
    const f16* bp = wcat + (size_t)(o0 + li) * C + lg * 8;
    f32x4 acc[4][4] = {};
    for (int ks = 0; ks < 16; ++ks) {
        f16x8 a4[4], b4[4];
#pragma unroll
        for (int t = 0; t < 4; ++t) a4[t] = *(const f16x8*)(ap + (size_t)(t * 16) * C + ks * 32);
#pragma unroll
        for (int t = 0; t < 4; ++t) b4[t] = *(const f16x8*)(bp + (size_t)(t * 16) * C + ks * 32);
#pragma unroll
        for (int tA = 0; tA < 4; ++tA)
#pragma unroll
            for (int tB = 0; tB < 4; ++tB)
                acc[tA][tB] = __builtin_amdgcn_mfma_f32_16x16x32_f16(a4[tA], b4[tB], acc[tA][tB], 0, 0, 0);
    }
#pragma unroll
    for (int tB = 0; tB < 4; ++tB) {
        int o = o0 + tB * 16 + li;
        float bias = bcat[o];
#pragma unroll
        for (int tA = 0; tA < 4; ++tA)
#pragma unroll
            for (int r = 0; r < 4; ++r) {
                int n = n0 + tA * 16 + lg * 4 + r;
                fk[(size_t)(b * N + n) * FKD + o] = (f16)(acc[tA][tB][r] + bias);
            }
    }
}

// ---------------------------------------------------------------- V projection (64c x 64n per wave)
__global__ void __launch_bounds__(256) proj_v(const f16* __restrict__ xt, const f16* __restrict__ wl,
                                              const float* __restrict__ wlb, f16* __restrict__ v) {
    int wid = blockIdx.x * 4 + (threadIdx.x >> 6);   // 2048 waves: b(2) ct(3) nt(6)
    int lane = threadIdx.x & 63;
    int li = lane & 15, lg = lane >> 4;
    int b  = wid >> 9;
    int ct = (wid >> 6) & 7;
    int nt = wid & 63;
    int c0 = ct * 64, n0 = nt * 64;
    const f16* ap = wl + (size_t)(c0 + li) * C + lg * 8;
    const f16* bp = xt + (size_t)(b * N + n0 + li) * C + lg * 8;
    f32x4 acc[4][4] = {};
    for (int ks = 0; ks < 16; ++ks) {
        f16x8 a4[4], b4[4];
#pragma unroll
        for (int t = 0; t < 4; ++t) a4[t] = *(const f16x8*)(ap + (size_t)(t * 16) * C + ks * 32);
#pragma unroll
        for (int t = 0; t < 4; ++t) b4[t] = *(const f16x8*)(bp + (size_t)(t * 16) * C + ks * 32);
#pragma unroll
        for (int tA = 0; tA < 4; ++tA)
#pragma unroll
            for (int tB = 0; tB < 4; ++tB)
                acc[tA][tB] = __builtin_amdgcn_mfma_f32_16x16x32_f16(a4[tA], b4[tB], acc[tA][tB], 0, 0, 0);
    }
#pragma unroll
    for (int tA = 0; tA < 4; ++tA)
#pragma unroll
        for (int r = 0; r < 4; ++r) {
            int c = c0 + tA * 16 + lg * 4 + r;
            float bias = wlb[c];
#pragma unroll
            for (int tB = 0; tB < 4; ++tB) {
                int n = n0 + tB * 16 + li;
                v[(size_t)(b * C + c) * N + n] = (f16)(acc[tA][tB][r] + bias);
            }
        }
}

// ---------------------------------------------------------------- flash attention + residual (v8)
// v4 geometry (256 blocks, 8 waves, 64q, XCD-pinned) with ONE barrier per j-tile:
// each wave exps with its OWN reference max M_w = max(ms, local_max) right after
// QK (no exchange wait), publishes (M_w, sum) + P; after the single barrier, PV
// rescales each P fragment by alpha = exp(M_w - ms) (per-lane scalar: fragment's
// 8 j-values lie in one 16-j slice). pbuf/smax/ssum double-buffered by t&1;
// kbuf double-buffered with global_load_lds staged at iter start.
__global__ void __launch_bounds__(512, 2) attn(const f16* __restrict__ fk, const f16* __restrict__ v,
                                               const float* __restrict__ x, const float* __restrict__ alphap,
                                               float* __restrict__ out) {
    __shared__ __align__(16) f16 kbuf[2][128 * 128];   // 64 KB
    __shared__ __align__(16) f16 pbuf[2][64 * 128];    // 32 KB
    __shared__ float smax[2][8][4][16];                // [buf][wave][f][i]  (M_w)
    __shared__ float ssum[2][8][4][16];

    const int tid  = threadIdx.x;
    const int wv   = tid >> 6;
    const int lane = tid & 63;
    const int li = lane & 15, lg = lane >> 4;
    const int swl = li & 7;
    // XCD-pinning: under blk%8 round-robin, each XCD sees a single batch
    const int v0 = blockIdx.x;
    const int b  = (v0 & 7) >> 1;
    const int it = ((v0 & 1) << 5) | (v0 >> 3);
    const int i0 = it * 64;
    const int c0 = wv * 64;

    // F fragments (B operand of swapped QK): col=i, k=ck; 4 i-frags
    f16x8 fb[4][4];
#pragma unroll
    for (int f = 0; f < 4; ++f) {
        const f16* fp = fk + (size_t)(b * N + i0 + f * 16 + li) * FKD + lg * 8;
#pragma unroll
        for (int ks = 0; ks < 4; ++ks) fb[f][ks] = *(const f16x8*)(fp + ks * 32);
    }

    // K staging via global_load_lds (proven v5/v7): wave wv -> rows [wv*16,wv*16+16).
    // LDS dest linear; global source granule inverse-swizzled li ^ (row&7).
    auto STAGE = [&](int tile) {
        f16* dst = &kbuf[tile & 1][0];
#pragma unroll
        for (int q = 0; q < 4; ++q) {
            const int row = wv * 16 + q * 4 + lg;
            const f16* gsrc = fk + (size_t)(b * N + tile * 128 + row) * FKD + CQ + (li ^ ((q * 4 + lg) & 7)) * 8;
            __builtin_amdgcn_global_load_lds(AS1(gsrc), AS3(dst + (wv * 16 + q * 4) * 128), 16, 0, 0);
        }
    };

    STAGE(0);
    const f16* vbase = v + (size_t)(b * C + c0 + li) * N + lg * 8;
    f32x4 oacc[4][4] = {};                       // [c-frag][i-frag]
    float ms[4] = {-1e30f, -1e30f, -1e30f, -1e30f};
    float ls[4] = {0.f, 0.f, 0.f, 0.f};
    __syncthreads();                             // tile 0 staged

    for (int t = 0; t < 32; ++t) {
        const int bsel = t & 1;
        const int j0 = t * 128;
        // (a) stage next K tile into the other buffer (drains at this iter's barrier)
        if (t < 31) STAGE(t + 1);
        // (b) QK for this wave's 16-j slice, all 4 i-frags
        const f16* kc = &kbuf[bsel][0];
        f16x8 kf4[4];
#pragma unroll
        for (int ks = 0; ks < 4; ++ks)
            kf4[ks] = *(const f16x8*)(&kc[(wv * 16 + li) * 128 + ((ks * 4 + lg) ^ swl) * 8]);
        f32x4 s[4] = {};
        __builtin_amdgcn_s_setprio(1);
#pragma unroll
        for (int ks = 0; ks < 4; ++ks)
#pragma unroll
            for (int f = 0; f < 4; ++f)
                s[f] = __builtin_amdgcn_mfma_f32_16x16x32_f16(kf4[ks], fb[f][ks], s[f], 0, 0, 0);
        __builtin_amdgcn_s_setprio(0);
        // (c) per-wave reference max M_w = max(ms, local max); publish
        float Mw[4];
#pragma unroll
        for (int f = 0; f < 4; ++f) {
            float t0 = fmaxf(fmaxf(s[f][0], s[f][1]), fmaxf(s[f][2], s[f][3]));
            t0 = fmaxf(t0, __shfl_xor(t0, 16));
            t0 = fmaxf(t0, __shfl_xor(t0, 32));
            Mw[f] = fmaxf(ms[f], t0);
            if (lane < 16) smax[bsel][wv][f][li] = Mw[f];
        }
        // (d) exp with OWN reference (no exchange wait) + P write + partial sum
        const int jl = wv * 16 + lg * 4;
        const int gg = (jl >> 3) ^ swl;
        f16* pb_w = &pbuf[bsel][0];
#pragma unroll
        for (int f = 0; f < 4; ++f) {
            f16x4 pk;
            float p0 = 0.f;
#pragma unroll
            for (int r = 0; r < 4; ++r) { float p = __expf(s[f][r] - Mw[f]); p0 += p; pk[r] = (f16)p; }
            *(f16x4*)(&pb_w[(f * 16 + li) * 128 + gg * 8 + (jl & 7)]) = pk;
            p0 += __shfl_xor(p0, 16);
            p0 += __shfl_xor(p0, 32);
            if (lane < 16) ssum[bsel][wv][f][li] = p0;
        }
        // V prefetch phase 0 (latency hides under the barrier)
        f16x8 va0[4], va1[4];
#pragma unroll
        for (int cf = 0; cf < 4; ++cf) va0[cf] = *(const f16x8*)(vbase + (size_t)(cf * 16) * N + j0);
        __syncthreads();   // THE barrier: P, M_w, ssum, next-K all visible
        // (e) stats: tile max, T13 rescale, l accumulation (per-lane query i=li)
#pragma unroll
        for (int f = 0; f < 4; ++f) {
            float mw0 = smax[bsel][0][f][li], mw1 = smax[bsel][1][f][li];
            float mw2 = smax[bsel][2][f][li], mw3 = smax[bsel][3][f][li];
            float mw4 = smax[bsel][4][f][li], mw5 = smax[bsel][5][f][li];
            float mw6 = smax[bsel][6][f][li], mw7 = smax[bsel][7][f][li];
            float mg = fmaxf(fmaxf(fmaxf(mw0, mw1), fmaxf(mw2, mw3)),
                             fmaxf(fmaxf(mw4, mw5), fmaxf(mw6, mw7)));
            if (!__all(mg <= ms[f] + 8.0f)) {
                float sc = __expf(ms[f] - mg);
                ms[f] = mg; ls[f] *= sc;
#pragma unroll
                for (int cf = 0; cf < 4; ++cf) oacc[cf][f] *= sc;
            }
            float S = ssum[bsel][0][f][li] * __expf(mw0 - ms[f]);
            S += ssum[bsel][1][f][li] * __expf(mw1 - ms[f]);
            S += ssum[bsel][2][f][li] * __expf(mw2 - ms[f]);
            S += ssum[bsel][3][f][li] * __expf(mw3 - ms[f]);
            S += ssum[bsel][4][f][li] * __expf(mw4 - ms[f]);
            S += ssum[bsel][5][f][li] * __expf(mw5 - ms[f]);
            S += ssum[bsel][6][f][li] * __expf(mw6 - ms[f]);
            S += ssum[bsel][7][f][li] * __expf(mw7 - ms[f]);
            ls[f] += S;
        }
        // V prefetch phase 1
#pragma unroll
        for (int cf = 0; cf < 4; ++cf) va1[cf] = *(const f16x8*)(vbase + (size_t)(cf * 16) * N + j0 + 32);
        // (f) PV over 128 j: fragment j-slice w = kf*2 + (lg>>1); alpha per lane
#pragma unroll
        for (int kf = 0; kf < 4; ++kf) {
            const int cur = kf & 1;
            const int pg = (kf * 4 + lg) ^ swl;
            const int w = kf * 2 + (lg >> 1);
            f16x8 pb[4];
#pragma unroll
            for (int f = 0; f < 4; ++f) {
                pb[f] = *(const f16x8*)(&pb_w[(f * 16 + li) * 128 + pg * 8]);
                float a = __expf(smax[bsel][w][f][li] - ms[f]);
                f16 ah = (f16)a;
#pragma unroll
                for (int e = 0; e < 8; ++e) pb[f][e] *= ah;
            }
            f16x8 vv0, vv1, vv2, vv3;
            if (kf & 1) { vv0 = va1[0]; vv1 = va1[1]; vv2 = va1[2]; vv3 = va1[3]; }
            else        { vv0 = va0[0]; vv1 = va0[1]; vv2 = va0[2]; vv3 = va0[3]; }
            if (kf < 2) {
#pragma unroll
                for (int cf = 0; cf < 4; ++cf) {
                    f16x8 nv = *(const f16x8*)(vbase + (size_t)(cf * 16) * N + j0 + (kf + 2) * 32);
                    if (kf & 1) va1[cf] = nv; else va0[cf] = nv;
                }
            }
            __builtin_amdgcn_s_setprio(1);
#pragma unroll
            for (int f = 0; f < 4; ++f) {
                oacc[0][f] = __builtin_amdgcn_mfma_f32_16x16x32_f16(vv0, pb[f], oacc[0][f], 0, 0, 0);
                oacc[1][f] = __builtin_amdgcn_mfma_f32_16x16x32_f16(vv1, pb[f], oacc[1][f], 0, 0, 0);
                oacc[2][f] = __builtin_amdgcn_mfma_f32_16x16x32_f16(vv2, pb[f], oacc[2][f], 0, 0, 0);
                oacc[3][f] = __builtin_amdgcn_mfma_f32_16x16x32_f16(vv3, pb[f], oacc[3][f], 0, 0, 0);
            }
            __builtin_amdgcn_s_setprio(0);
        }
        // no 2nd barrier: buffers for t+1 are the other halves; next barrier orders reuse
    }

    // epilogue: O[c][i], i coalesced over li; + residual
    const float alpha = alphap[0];
#pragma unroll
    for (int f = 0; f < 4; ++f) {
        const float invf = alpha / ls[f];
        const float* xp = x + (size_t)(b * C + c0) * N + i0 + f * 16 + li;
        float* op = out + (size_t)(b * C + c0) * N + i0 + f * 16 + li;
#pragma unroll
        for (int cf = 0; cf < 4; ++cf)
#pragma unroll
            for (int r = 0; r < 4; ++r) {
                const int cl = cf * 16 + lg * 4 + r;
                op[(size_t)cl * N] = oacc[cf][f][r] * invf + xp[(size_t)cl * N];
            }
    }
}

extern "C" void kernel_launch(void* const* d_in, const int* in_sizes, int n_in,
                              void* d_out, int out_size, void* d_ws, size_t ws_size,
                              hipStream_t stream) {
    const float* x     = (const float*)d_in[0];
    const float* Wf_w  = (const float*)d_in[1];
    const float* Wf_b  = (const float*)d_in[2];
    const float* Wh_w  = (const float*)d_in[3];
    const float* Wh_b  = (const float*)d_in[4];
    const float* Wl_w  = (const float*)d_in[5];
    const float* Wl_b  = (const float*)d_in[6];
    const float* alpha = (const float*)d_in[7];
    char* ws = (char*)d_ws;
    f16*   xt   = (f16*)(ws + WS_XT);
    f16*   fkb  = (f16*)(ws + WS_FK);
    f16*   vb   = (f16*)(ws + WS_V);
    f16*   wcat = (f16*)(ws + WS_WCAT);
    f16*   wl   = (f16*)(ws + WS_WL);
    float* bcat = (float*)(ws + WS_BC);
    float* out  = (float*)d_out;

    prep_weights<<<dim3((C * C + 255) / 256), dim3(256), 0, stream>>>(Wf_w, Wf_b, Wh_w, Wh_b, Wl_w, wcat, wl, bcat);
    transpose_x<<<dim3(BATCH * 8 * 64), dim3(256), 0, stream>>>(x, xt);
    proj_fk<<<dim3(256), dim3(256), 0, stream>>>(xt, wcat, bcat, fkb);
    proj_v<<<dim3(512), dim3(256), 0, stream>>>(xt, wl, Wl_b, vb);
    // 4 b x 64 query-tiles(64q) = 256 blocks x 8 waves = 1 block/CU, XCD-pinned
    attn<<<dim3(256), dim3(512), 0, stream>>>(fkb, vb, x, alpha, out);
}

// Round 9
// 239.696 us; speedup vs baseline: 1.8055x; 1.0264x over previous
//
#include <hip/hip_runtime.h>
#include <hip/hip_bf16.h>

typedef _Float16 f16;
typedef _Float16 f16x4 __attribute__((ext_vector_type(4)));
typedef _Float16 f16x8 __attribute__((ext_vector_type(8)));
typedef float f32x4 __attribute__((ext_vector_type(4)));

constexpr int BATCH = 4, C = 512, CQ = 128, N = 4096;
constexpr int FKD = 256; // f(128) + k(128) channels, stacked

// workspace layout (bytes)
constexpr size_t WS_XT   = 0;                                      // f16 [B][N][C]   16 MB
constexpr size_t WS_FK   = WS_XT   + (size_t)BATCH * N * C * 2;    // f16 [B][N][256]  8 MB
constexpr size_t WS_V    = WS_FK   + (size_t)BATCH * N * FKD * 2;  // f16 [B][C][N]   16 MB
constexpr size_t WS_WCAT = WS_V    + (size_t)BATCH * C * N * 2;    // f16 [256][512]
constexpr size_t WS_WL   = WS_WCAT + (size_t)FKD * C * 2;          // f16 [512][512]
constexpr size_t WS_BC   = WS_WL   + (size_t)C * C * 2;            // f32 [256]

#define AS1(p) ((const __attribute__((address_space(1))) void*)(p))
#define AS3(p) ((__attribute__((address_space(3))) void*)(p))

// ---------------------------------------------------------------- weights->fp16
__global__ void prep_weights(const float* __restrict__ Wf_w, const float* __restrict__ Wf_b,
                             const float* __restrict__ Wh_w, const float* __restrict__ Wh_b,
                             const float* __restrict__ Wl_w,
                             f16* __restrict__ wcat, f16* __restrict__ wl, float* __restrict__ bcat) {
    int i = blockIdx.x * 256 + threadIdx.x;                 // grid covers C*C
    if (i < FKD * C) {
        int o = i >> 9, c = i & 511;
        float v = (o < CQ) ? Wf_w[o * C + c] : Wh_w[(o - CQ) * C + c];
        wcat[i] = (f16)v;
    }
    if (i < C * C) wl[i] = (f16)Wl_w[i];
    if (i < FKD) bcat[i] = (i < CQ) ? Wf_b[i] : Wh_b[i - CQ];
}

// ---------------------------------------------------------------- x (B,C,N) f32 -> xT (B,N,C) f16
__global__ void transpose_x(const float* __restrict__ x, f16* __restrict__ xt) {
    __shared__ float tile[64][65];
    int gid = blockIdx.x;
    int b = gid >> 9, rem = gid & 511;
    int c0 = (rem >> 6) * 64, n0 = (rem & 63) * 64;
    int t = threadIdx.x;
    int tn = t & 63, tg = t >> 6;
    const float* xp = x + (size_t)b * C * N + (size_t)c0 * N + n0;
#pragma unroll
    for (int r = 0; r < 16; ++r) {
        int cl = tg + r * 4;
        tile[cl][tn] = xp[(size_t)cl * N + tn];
    }
    __syncthreads();
    f16* xo = xt + (size_t)b * N * C + (size_t)n0 * C + c0;
#pragma unroll
    for (int r = 0; r < 16; ++r) {
        int nl = tg + r * 4;
        xo[(size_t)nl * C + tn] = (f16)tile[tn][nl];
    }
}

// ---------------------------------------------------------------- FK projection (64n x 64o per wave)
__global__ void __launch_bounds__(256) proj_fk(const f16* __restrict__ xt, const f16* __restrict__ wcat,
                                               const float* __restrict__ bcat, f16* __restrict__ fk) {
    int wid = blockIdx.x * 4 + (threadIdx.x >> 6);   // 1024 waves: b(2) nt(6) ot(2)
    int lane = threadIdx.x & 63;
    int li = lane & 15, lg = lane >> 4;
    int b  = wid >> 8;
    int nt = (wid >> 2) & 63;
    int ot = wid & 3;
    int n0 = nt * 64, o0 = ot * 64;
    const f16* ap = xt + (size_t)(b * N + n0 + li) * C + lg * 8;
    const f16* bp = wcat + (size_t)(o0 + li) * C + lg * 8;
    f32x4 acc[4][4] = {};
    for (int ks = 0; ks < 16; ++ks) {
        f16x8 a4[4], b4[4];
#pragma unroll
        for (int t = 0; t < 4; ++t) a4[t] = *(const f16x8*)(ap + (size_t)(t * 16) * C + ks * 32);
#pragma unroll
        for (int t = 0; t < 4; ++t) b4[t] = *(const f16x8*)(bp + (size_t)(t * 16) * C + ks * 32);
#pragma unroll
        for (int tA = 0; tA < 4; ++tA)
#pragma unroll
            for (int tB = 0; tB < 4; ++tB)
                acc[tA][tB] = __builtin_amdgcn_mfma_f32_16x16x32_f16(a4[tA], b4[tB], acc[tA][tB], 0, 0, 0);
    }
#pragma unroll
    for (int tB = 0; tB < 4; ++tB) {
        int o = o0 + tB * 16 + li;
        float bias = bcat[o];
#pragma unroll
        for (int tA = 0; tA < 4; ++tA)
#pragma unroll
            for (int r = 0; r < 4; ++r) {
                int n = n0 + tA * 16 + lg * 4 + r;
                fk[(size_t)(b * N + n) * FKD + o] = (f16)(acc[tA][tB][r] + bias);
            }
    }
}

// ---------------------------------------------------------------- V projection (64c x 64n per wave)
__global__ void __launch_bounds__(256) proj_v(const f16* __restrict__ xt, const f16* __restrict__ wl,
                                              const float* __restrict__ wlb, f16* __restrict__ v) {
    int wid = blockIdx.x * 4 + (threadIdx.x >> 6);   // 2048 waves: b(2) ct(3) nt(6)
    int lane = threadIdx.x & 63;
    int li = lane & 15, lg = lane >> 4;
    int b  = wid >> 9;
    int ct = (wid >> 6) & 7;
    int nt = wid & 63;
    int c0 = ct * 64, n0 = nt * 64;
    const f16* ap = wl + (size_t)(c0 + li) * C + lg * 8;
    const f16* bp = xt + (size_t)(b * N + n0 + li) * C + lg * 8;
    f32x4 acc[4][4] = {};
    for (int ks = 0; ks < 16; ++ks) {
        f16x8 a4[4], b4[4];
#pragma unroll
        for (int t = 0; t < 4; ++t) a4[t] = *(const f16x8*)(ap + (size_t)(t * 16) * C + ks * 32);
#pragma unroll
        for (int t = 0; t < 4; ++t) b4[t] = *(const f16x8*)(bp + (size_t)(t * 16) * C + ks * 32);
#pragma unroll
        for (int tA = 0; tA < 4; ++tA)
#pragma unroll
            for (int tB = 0; tB < 4; ++tB)
                acc[tA][tB] = __builtin_amdgcn_mfma_f32_16x16x32_f16(a4[tA], b4[tB], acc[tA][tB], 0, 0, 0);
    }
#pragma unroll
    for (int tA = 0; tA < 4; ++tA)
#pragma unroll
        for (int r = 0; r < 4; ++r) {
            int c = c0 + tA * 16 + lg * 4 + r;
            float bias = wlb[c];
#pragma unroll
            for (int tB = 0; tB < 4; ++tB) {
                int n = n0 + tB * 16 + li;
                v[(size_t)(b * C + c) * N + n] = (f16)(acc[tA][tB][r] + bias);
            }
        }
}

// ---------------------------------------------------------------- flash attention + residual (v9)
// v4 softmax/dataflow, KVBLK=256: 8 waves, 64q tile, 256 blocks XCD-pinned.
// Wave wv: QK rows j in [wv*32, wv*32+32) (2 slices); PV c-slice [wv*64, +64).
// K: SINGLE 64KB kbuf, staged by global_load_lds (linear dest, inverse-swizzled
// source). Hazards: QK(t) reads done before barA; K(t+1) issued after barA,
// drained at barB, read after barB at t+1. pbuf[64][256] granule-XOR swizzled.
// 2 barriers per 256-j tile = half of v4's sync rate, same exp/MFMA per j.
__global__ void __launch_bounds__(512, 2) attn(const f16* __restrict__ fk, const f16* __restrict__ v,
                                               const float* __restrict__ x, const float* __restrict__ alphap,
                                               float* __restrict__ out) {
    __shared__ __align__(16) f16 kbuf[256 * 128];      // 64 KB, single buffer
    __shared__ __align__(16) f16 pbuf[64 * 256];       // 32 KB shared P
    __shared__ float smax[8][4][16];
    __shared__ float ssum[8][4][16];

    const int tid  = threadIdx.x;
    const int wv   = tid >> 6;
    const int lane = tid & 63;
    const int li = lane & 15, lg = lane >> 4;
    const int swl = li & 7;
    // XCD-pinning: under blk%8 round-robin, each XCD sees a single batch
    const int v0 = blockIdx.x;
    const int b  = (v0 & 7) >> 1;
    const int it = ((v0 & 1) << 5) | (v0 >> 3);
    const int i0 = it * 64;
    const int c0 = wv * 64;

    // F fragments (B operand of swapped QK): col=i, k=ck; 4 i-frags
    f16x8 fb[4][4];
#pragma unroll
    for (int f = 0; f < 4; ++f) {
        const f16* fp = fk + (size_t)(b * N + i0 + f * 16 + li) * FKD + lg * 8;
#pragma unroll
        for (int ks = 0; ks < 4; ++ks) fb[f][ks] = *(const f16x8*)(fp + ks * 32);
    }

    // K staging: wave wv stages rows [wv*32, wv*32+32), 8 gld_lds (16B/lane).
    // LDS dest linear (lane -> row lg, granule li); source granule li ^ (row&7).
    auto STAGE = [&](int tile) {
#pragma unroll
        for (int q = 0; q < 8; ++q) {
            const int row = wv * 32 + q * 4 + lg;
            const f16* gsrc = fk + (size_t)(b * N + tile * 256 + row) * FKD + CQ + (li ^ ((q * 4 + lg) & 7)) * 8;
            __builtin_amdgcn_global_load_lds(AS1(gsrc), AS3(&kbuf[(wv * 32 + q * 4) * 128]), 16, 0, 0);
        }
    };

    STAGE(0);
    const f16* vbase = v + (size_t)(b * C + c0 + li) * N + lg * 8;
    f32x4 oacc[4][4] = {};                       // [c-frag][i-frag]
    float ms[4] = {-1e30f, -1e30f, -1e30f, -1e30f};
    float ls[4] = {0.f, 0.f, 0.f, 0.f};
    __syncthreads();                             // tile 0 staged

    for (int t = 0; t < 16; ++t) {
        const int j0 = t * 256;
        // (a) QK for this wave's 32-j rows (2 slices), all 4 i-frags
        f32x4 s[2][4] = {};
#pragma unroll
        for (int sl = 0; sl < 2; ++sl) {
            f16x8 kf4[4];
#pragma unroll
            for (int ks = 0; ks < 4; ++ks)
                kf4[ks] = *(const f16x8*)(&kbuf[(wv * 32 + sl * 16 + li) * 128 + ((ks * 4 + lg) ^ swl) * 8]);
            __builtin_amdgcn_s_setprio(1);
#pragma unroll
            for (int ks = 0; ks < 4; ++ks)
#pragma unroll
                for (int f = 0; f < 4; ++f)
                    s[sl][f] = __builtin_amdgcn_mfma_f32_16x16x32_f16(kf4[ks], fb[f][ks], s[sl][f], 0, 0, 0);
            __builtin_amdgcn_s_setprio(0);
        }
        // (b) wave-local max over 32 j per query; publish
#pragma unroll
        for (int f = 0; f < 4; ++f) {
            float t0 = fmaxf(fmaxf(s[0][f][0], s[0][f][1]), fmaxf(s[0][f][2], s[0][f][3]));
            float t1 = fmaxf(fmaxf(s[1][f][0], s[1][f][1]), fmaxf(s[1][f][2], s[1][f][3]));
            t0 = fmaxf(t0, t1);
            t0 = fmaxf(t0, __shfl_xor(t0, 16));
            t0 = fmaxf(t0, __shfl_xor(t0, 32));
            if (lane < 16) smax[wv][f][li] = t0;
        }
        __syncthreads();   // barA: QK reads of kbuf done; smax visible
        // (c) stage K(t+1) into kbuf (drains at barB; read only after barB, t+1)
        if (t < 15) STAGE(t + 1);
        // (d) global max + T13 rescale
        float gm[4];
#pragma unroll
        for (int f = 0; f < 4; ++f) {
            float m0 = smax[0][f][li];
#pragma unroll
            for (int w = 1; w < 8; ++w) m0 = fmaxf(m0, smax[w][f][li]);
            gm[f] = m0;
        }
#pragma unroll
        for (int f = 0; f < 4; ++f) {
            if (!__all(gm[f] <= ms[f] + 8.0f)) {
                float mn = fmaxf(ms[f], gm[f]), sc = __expf(ms[f] - mn);
                ms[f] = mn; ls[f] *= sc;
#pragma unroll
                for (int cf = 0; cf < 4; ++cf) oacc[cf][f] *= sc;
            }
        }
        // (e) exp (8 j per lane per f) + P write + partial sums
#pragma unroll
        for (int f = 0; f < 4; ++f) {
            float p0 = 0.f;
#pragma unroll
            for (int sl = 0; sl < 2; ++sl) {
                const int jl = wv * 32 + sl * 16 + lg * 4;
                const int gg = (jl >> 3) ^ swl;
                f16x4 pk;
#pragma unroll
                for (int r = 0; r < 4; ++r) { float p = __expf(s[sl][f][r] - ms[f]); p0 += p; pk[r] = (f16)p; }
                *(f16x4*)(&pbuf[(f * 16 + li) * 256 + gg * 8 + (jl & 7)]) = pk;
            }
            p0 += __shfl_xor(p0, 16);
            p0 += __shfl_xor(p0, 32);
            if (lane < 16) ssum[wv][f][li] = p0;
        }
        // V prefetch phase 0 (latency hides under barB)
        f16x8 va0[4], va1[4];
#pragma unroll
        for (int cf = 0; cf < 4; ++cf) va0[cf] = *(const f16x8*)(vbase + (size_t)(cf * 16) * N + j0);
        __syncthreads();   // barB: P + ssum visible; K(t+1) staged
        // (f) accumulate l
#pragma unroll
        for (int f = 0; f < 4; ++f) {
            float a0 = 0.f;
#pragma unroll
            for (int w = 0; w < 8; ++w) a0 += ssum[w][f][li];
            ls[f] += a0;
        }
        // (g) PV over 256 j: 8 phases, rolling 2-deep V prefetch
#pragma unroll
        for (int cf = 0; cf < 4; ++cf) va1[cf] = *(const f16x8*)(vbase + (size_t)(cf * 16) * N + j0 + 32);
#pragma unroll
        for (int kf = 0; kf < 8; ++kf) {
            const int pg = (kf * 4 + lg) ^ swl;
            f16x8 pb[4];
#pragma unroll
            for (int f = 0; f < 4; ++f)
                pb[f] = *(const f16x8*)(&pbuf[(f * 16 + li) * 256 + pg * 8]);
            f16x8 vv0, vv1, vv2, vv3;
            if (kf & 1) { vv0 = va1[0]; vv1 = va1[1]; vv2 = va1[2]; vv3 = va1[3]; }
            else        { vv0 = va0[0]; vv1 = va0[1]; vv2 = va0[2]; vv3 = va0[3]; }
            if (kf < 6) {
#pragma unroll
                for (int cf = 0; cf < 4; ++cf) {
                    f16x8 nv = *(const f16x8*)(vbase + (size_t)(cf * 16) * N + j0 + (kf + 2) * 32);
                    if (kf & 1) va1[cf] = nv; else va0[cf] = nv;
                }
            }
            __builtin_amdgcn_s_setprio(1);
#pragma unroll
            for (int f = 0; f < 4; ++f) {
                oacc[0][f] = __builtin_amdgcn_mfma_f32_16x16x32_f16(vv0, pb[f], oacc[0][f], 0, 0, 0);
                oacc[1][f] = __builtin_amdgcn_mfma_f32_16x16x32_f16(vv1, pb[f], oacc[1][f], 0, 0, 0);
                oacc[2][f] = __builtin_amdgcn_mfma_f32_16x16x32_f16(vv2, pb[f], oacc[2][f], 0, 0, 0);
                oacc[3][f] = __builtin_amdgcn_mfma_f32_16x16x32_f16(vv3, pb[f], oacc[3][f], 0, 0, 0);
            }
            __builtin_amdgcn_s_setprio(0);
        }
        // pbuf reads of tile t finish before barA(t+1); writes of t+1 occur after it
    }

    // epilogue: O[c][i], i coalesced over li; + residual
    const float alpha = alphap[0];
#pragma unroll
    for (int f = 0; f < 4; ++f) {
        const float invf = alpha / ls[f];
        const float* xp = x + (size_t)(b * C + c0) * N + i0 + f * 16 + li;
        float* op = out + (size_t)(b * C + c0) * N + i0 + f * 16 + li;
#pragma unroll
        for (int cf = 0; cf < 4; ++cf)
#pragma unroll
            for (int r = 0; r < 4; ++r) {
                const int cl = cf * 16 + lg * 4 + r;
                op[(size_t)cl * N] = oacc[cf][f][r] * invf + xp[(size_t)cl * N];
            }
    }
}

extern "C" void kernel_launch(void* const* d_in, const int* in_sizes, int n_in,
                              void* d_out, int out_size, void* d_ws, size_t ws_size,
                              hipStream_t stream) {
    const float* x     = (const float*)d_in[0];
    const float* Wf_w  = (const float*)d_in[1];
    const float* Wf_b  = (const float*)d_in[2];
    const float* Wh_w  = (const float*)d_in[3];
    const float* Wh_b  = (const float*)d_in[4];
    const float* Wl_w  = (const float*)d_in[5];
    const float* Wl_b  = (const float*)d_in[6];
    const float* alpha = (const float*)d_in[7];
    char* ws = (char*)d_ws;
    f16*   xt   = (f16*)(ws + WS_XT);
    f16*   fkb  = (f16*)(ws + WS_FK);
    f16*   vb   = (f16*)(ws + WS_V);
    f16*   wcat = (f16*)(ws + WS_WCAT);
    f16*   wl   = (f16*)(ws + WS_WL);
    float* bcat = (float*)(ws + WS_BC);
    float* out  = (float*)d_out;

    prep_weights<<<dim3((C * C + 255) / 256), dim3(256), 0, stream>>>(Wf_w, Wf_b, Wh_w, Wh_b, Wl_w, wcat, wl, bcat);
    transpose_x<<<dim3(BATCH * 8 * 64), dim3(256), 0, stream>>>(x, xt);
    proj_fk<<<dim3(256), dim3(256), 0, stream>>>(xt, wcat, bcat, fkb);
    proj_v<<<dim3(512), dim3(256), 0, stream>>>(xt, wl, Wl_b, vb);
    // 4 b x 64 query-tiles(64q) = 256 blocks x 8 waves = 1 block/CU, XCD-pinned
    attn<<<dim3(256), dim3(512), 0, stream>>>(fkb, vb, x, alpha, out);
}